// Round 7
// baseline (53.035 us; speedup 1.0000x reference)
//
#include <hip/hip_runtime.h>
#include <cstdint>

typedef unsigned long long u64;
typedef unsigned short ushort_t;
typedef __attribute__((ext_vector_type(8))) short short8;   // 8 bf16 = 4 VGPR
typedef __attribute__((ext_vector_type(4))) float f32x4;

#define RFL(x) __builtin_amdgcn_readfirstlane(x)

__device__ __forceinline__ unsigned short f2bf(float f) {   // RNE f32->bf16
    union { float f; unsigned u; } v; v.f = f;
    unsigned r = v.u + 0x7FFFu + ((v.u >> 16) & 1u);
    return (unsigned short)(r >> 16);
}
__device__ __forceinline__ float bf2f(unsigned short h) {
    union { float f; unsigned u; } v; v.u = ((unsigned)h) << 16;
    return v.f;
}

__device__ __forceinline__ void gload_lds16(const void* g, void* l) {
    __builtin_amdgcn_global_load_lds(
        (const __attribute__((address_space(1))) unsigned int*)g,
        (__attribute__((address_space(3))) unsigned int*)l, 16, 0, 0);
}

// Dims: B=2, S=1024, C=512, H=8, hd=64, T=4.
// bits layout: [3(qkv)][4(t)][2(b)][8(h)][1024(s)] u64 (bit d = channel h*64+d)
// vt   layout: [2(b)][8(h)][4(t)][16(w)][64(d)]  u64
// ws: bits 1.5MiB | vt 0.5MiB | xh 2MiB | xl 2MiB | wh 1.5MiB | wl 1.5MiB = 9MiB

#define AH_OFF 0
#define AL_OFF 8192
#define BH_OFF 16384
#define BL_OFF 24576

// ---------------- Kernel C: one-shot f32 -> split-bf16 (hi/lo) conversion.
// Blocks 0..511: x (2048x512). Blocks 512..895: Wq|Wk|Wv concat (1536x512).
// Same f2bf math as R4/R5's in-loop conversion -> operands bitwise identical.
__global__ __launch_bounds__(256) void cvt_split(
    const float* __restrict__ x,
    const float* __restrict__ Wq, const float* __restrict__ Wk,
    const float* __restrict__ Wv,
    ushort_t* __restrict__ xh, ushort_t* __restrict__ xl,
    ushort_t* __restrict__ wh, ushort_t* __restrict__ wl)
{
    const int bid = blockIdx.x;
    const float* s;
    ushort_t *hd, *ld;
    if (bid < 512) {
        const size_t j = (size_t)bid * 2048 + (size_t)threadIdx.x * 8;
        s = x + j; hd = xh + j; ld = xl + j;
    } else {
        const size_t j = (size_t)(bid - 512) * 2048 + (size_t)threadIdx.x * 8;
        const int mat = (int)(j >> 18);           // 512*512 elems per matrix
        const size_t off = j & 262143;
        s = ((mat == 0) ? Wq : (mat == 1) ? Wk : Wv) + off;
        hd = wh + j; ld = wl + j;
    }
    const float4 a = *(const float4*)s;
    const float4 b = *(const float4*)(s + 4);
    const float va[8] = {a.x, a.y, a.z, a.w, b.x, b.y, b.z, b.w};
    short8 h8, l8;
#pragma unroll
    for (int i = 0; i < 8; ++i) {
        const unsigned short hi = f2bf(va[i]);
        h8[i] = (short)hi;
        l8[i] = (short)f2bf(va[i] - bf2f(hi));
    }
    *(short8*)hd = h8;
    *(short8*)ld = l8;
}

// ---------------- MFMA GEMM v2: pre-split bf16 operands, global_load_lds
// staging (linear LDS dest + inverse-swizzled global source, rule #21),
// swizzled ds_read (unchanged from R4), LIF + ballot pack epilogue.
// y accumulation order identical to R4/R5 -> bitwise-identical spikes.
__global__ __launch_bounds__(256) void gemm_mfma_lif_pack2(
    const ushort_t* __restrict__ xh, const ushort_t* __restrict__ xl,
    const ushort_t* __restrict__ wh, const ushort_t* __restrict__ wl,
    u64* __restrict__ bits)
{
    __shared__ __align__(16) char smem[32768];

    const int tid  = threadIdx.x;
    const int lane = tid & 63;
    const int wv   = RFL(tid >> 6);
    const int bx  = blockIdx.x;     // 32 row tiles of 64
    const int byn = blockIdx.y;     // 24 = 3 mat * 8 heads
    const int mat = byn >> 3, h = byn & 7;

    const int wm = wv >> 1, wn = wv & 1;
    const int lg = lane >> 4, lr = lane & 15;

    // staging source offsets: lane l writes LDS slot_sw=(l&7) of row
    // stripe*8+(l>>3); logical slot there is (l&7)^(l>>3) -> read that
    // slot from global so that the read-side XOR sees logical data.
    const int lrow8 = lane >> 3;
    const int koff  = ((lane & 7) ^ lrow8) * 8;   // bf16 elems within 64-k chunk

    f32x4 acc[2][2] = {{{0.f,0.f,0.f,0.f},{0.f,0.f,0.f,0.f}},
                       {{0.f,0.f,0.f,0.f},{0.f,0.f,0.f,0.f}}};

    for (int k0 = 0; k0 < 512; k0 += 64) {
        // ---- stage 4 bf16 tiles (64x64 each): 2 stripes/wave/tile
#pragma unroll
        for (int sp = 0; sp < 2; ++sp) {
            const int stripe = wv * 2 + sp;            // wave-uniform
            const int row = stripe * 8 + lrow8;
            const size_t aoff = (size_t)(bx * 64 + row) * 512 + k0 + koff;
            const size_t boff = (size_t)(byn * 64 + row) * 512 + k0 + koff;
            gload_lds16(xh + aoff, smem + AH_OFF + stripe * 1024);
            gload_lds16(xl + aoff, smem + AL_OFF + stripe * 1024);
            gload_lds16(wh + boff, smem + BH_OFF + stripe * 1024);
            gload_lds16(wl + boff, smem + BL_OFF + stripe * 1024);
        }
        __syncthreads();

        // ---- compute: 2 x (K=32) mfma steps, 3 split-bf16 passes each
#pragma unroll
        for (int kk = 0; kk < 64; kk += 32) {
            const int slotb = (kk >> 3) + lg;
            short8 ah[2], al[2], bh2[2], bl2[2];
#pragma unroll
            for (int fm = 0; fm < 2; ++fm) {
                const int row = wm * 32 + fm * 16 + lr;
                const int off = row * 128 + ((slotb ^ (row & 7)) << 4);
                ah[fm] = *(const short8*)(smem + AH_OFF + off);
                al[fm] = *(const short8*)(smem + AL_OFF + off);
            }
#pragma unroll
            for (int fn = 0; fn < 2; ++fn) {
                const int row = wn * 32 + fn * 16 + lr;
                const int off = row * 128 + ((slotb ^ (row & 7)) << 4);
                bh2[fn] = *(const short8*)(smem + BH_OFF + off);
                bl2[fn] = *(const short8*)(smem + BL_OFF + off);
            }
#pragma unroll
            for (int fm = 0; fm < 2; ++fm)
#pragma unroll
                for (int fn = 0; fn < 2; ++fn) {
                    acc[fm][fn] = __builtin_amdgcn_mfma_f32_16x16x32_bf16(
                        ah[fm], bh2[fn], acc[fm][fn], 0, 0, 0);
                    acc[fm][fn] = __builtin_amdgcn_mfma_f32_16x16x32_bf16(
                        ah[fm], bl2[fn], acc[fm][fn], 0, 0, 0);
                    acc[fm][fn] = __builtin_amdgcn_mfma_f32_16x16x32_bf16(
                        al[fm], bh2[fn], acc[fm][fn], 0, 0, 0);
                }
        }
        __syncthreads();
    }

    // ---- epilogue: y tile -> LDS (f32, pad 65), then LIF + ballot pack.
    float* yl = (float*)smem;
#pragma unroll
    for (int fm = 0; fm < 2; ++fm)
#pragma unroll
        for (int fn = 0; fn < 2; ++fn)
#pragma unroll
            for (int reg = 0; reg < 4; ++reg) {
                const int m_loc = wm * 32 + fm * 16 + lg * 4 + reg;  // row=(lane>>4)*4+reg
                const int n_loc = wn * 32 + fn * 16 + lr;            // col=lane&15
                yl[m_loc * 65 + n_loc] = acc[fm][fn][reg];
            }
    __syncthreads();

    for (int r = 0; r < 16; ++r) {
        const int lrow = wv * 16 + r;
        const float y = yl[lrow * 65 + lane];   // lane = channel d within head
        float v = 0.f;
        int sp[4];
#pragma unroll
        for (int t = 0; t < 4; ++t) {
            v = v + (y - v) * 0.5f;             // decay_input charge, tau=2
            const int s = (v - 1.0f >= 0.f) ? 1 : 0;
            v = s ? 0.f : v;                    // hard reset
            sp[t] = s;
        }
        const int grow = bx * 64 + lrow;
        const int bb = grow >> 10;
        const int ss = grow & 1023;
        u64* dst = bits + (((size_t)(mat * 4) * 2 + bb) * 8 + h) * 1024 + ss;
#pragma unroll
        for (int t = 0; t < 4; ++t) {
            const u64 msk = __ballot(sp[t]);
            if (lane == 0) dst[(size_t)t * (2 * 8 * 1024)] = msk;
        }
    }
}

// ---------------- Kernel T2: bit-transpose of v spikes (unchanged)
__global__ __launch_bounds__(256) void v_transpose2(
    const u64* __restrict__ bits,
    u64* __restrict__ vt)
{
    const int lane = threadIdx.x & 63;
    const int t  = threadIdx.x >> 6;
    const int b  = blockIdx.x;
    const int h  = blockIdx.y;
    const int wg = blockIdx.z;
    const u64* __restrict__ src = bits + (((size_t)(2 * 4 + t) * 2 + b) * 8 + h) * 1024;
    u64* __restrict__ dst = vt + (((size_t)b * 8 + h) * 4 + t) * 1024;
    for (int wi = 0; wi < 4; ++wi) {
        const int w = wg * 4 + wi;
        const u64 vword = src[(w << 6) + lane];
        u64 myword = 0;
#pragma unroll
        for (int d = 0; d < 64; ++d) {
            const u64 m = __ballot((int)((vword >> d) & 1ull));
            if (lane == d) myword = m;
        }
        dst[(w << 6) + lane] = myword;
    }
}

// ---------------- Kernel B4: two-level conservative screen + exact slow path
// (unchanged from R5).
__global__ __launch_bounds__(256) void spike_attn4(
    const u64* __restrict__ bits,
    const u64* __restrict__ vt,
    float* __restrict__ out)
{
    const int lane = threadIdx.x & 63;
    const int wave = RFL((int)(threadIdx.x >> 6));
    const int rt = blockIdx.x;   // 64 tiles of 16 rows
    const int h  = blockIdx.y;
    const int b  = blockIdx.z;

    const int bh = b * 8 + h;
    const u64* __restrict__ qb  = bits + (size_t)bh * 1024;
    const u64* __restrict__ kb  = bits + (size_t)(64 + bh) * 1024;
    const u64* __restrict__ vtb = vt + (size_t)bh * 4096;

    int cs[4] = {0, 0, 0, 0};
    for (int w = 0; w < 16; ++w) {
#pragma unroll
        for (int t = 0; t < 4; ++t)
            cs[t] += (int)__popcll(vtb[t * 1024 + (w << 6) + lane]);
    }
    const float base = (float)(cs[0] + cs[1] + cs[2] + cs[3]) * (1.0f / 4096.0f);

    const float E1 = 0.36787944117144233f;  // expf(-1)
    const int s0 = rt * 16 + wave * 4;      // 4 rows per wave

#pragma unroll
    for (int r = 0; r < 4; ++r) {
        const int s = s0 + r;
        const u64 q0 = qb[s];
        const u64 q1 = qb[16384 + s];
        const u64 q2 = qb[32768 + s];
        const u64 q3 = qb[49152 + s];
        const int c0 = (int)__popcll(q0), c1 = (int)__popcll(q1);
        const int c2 = (int)__popcll(q2), c3 = (int)__popcll(q3);

        // level-1: LIF recurrence on c_t (upper bound on u_t, floors included)
        unsigned B = (unsigned)(c0 << 2);
        unsigned mB = B;
        B = (B >> 1) + (unsigned)(c1 << 2); mB = max(mB, B);
        B = (B >> 1) + (unsigned)(c2 << 2); mB = max(mB, B);
        B = (B >> 1) + (unsigned)(c3 << 2); mB = max(mB, B);

        float o = base;
        if (mB >= 64u) {            // wave-uniform; minority of rows
            // level-2: exact per-k screen, max_t pc_t >= 9 anywhere?
            u64 any = 0;
            for (int w = 0; w < 16; ++w) {
                const int ko = (w << 6) + lane;
                const int pc0 = (int)__popcll(kb[ko]          & q0);
                const int pc1 = (int)__popcll(kb[16384 + ko] & q1);
                const int pc2 = (int)__popcll(kb[32768 + ko] & q2);
                const int pc3 = (int)__popcll(kb[49152 + ko] & q3);
                const int mx = max(max(pc0, pc1), max(pc2, pc3));
                any |= __ballot(mx >= 9);
            }
            if (any) {              // wave-uniform; essentially never
                int msum[4] = {0, 0, 0, 0}, n11[4] = {0, 0, 0, 0};
                for (int w = 0; w < 16; ++w) {
                    const int ko = (w << 6) + lane;
                    const int pcs[4] = {
                        (int)__popcll(kb[ko]          & q0),
                        (int)__popcll(kb[16384 + ko] & q1),
                        (int)__popcll(kb[32768 + ko] & q2),
                        (int)__popcll(kb[49152 + ko] & q3)};
                    unsigned u = 0;
#pragma unroll
                    for (int t = 0; t < 4; ++t) {
                        u = (u >> 1) + (unsigned)(pcs[t] << 2);  // 64ths; exact
                        const int spk = (u >= 64u) ? 1 : 0;
                        const u64 msk = __ballot(spk);
                        u = spk ? 0u : u;
                        msum[t] += (int)__popcll(msk);
                        n11[t]  += (int)__popcll(msk & vtb[t * 1024 + ko]);
                    }
                }
                o = 0.f;
#pragma unroll
                for (int t = 0; t < 4; ++t) {
                    const float mf = (float)msum[t];
                    const float Z  = mf + (1024.f - mf) * E1;
                    const float p1 = 1.0f / Z;
                    const float p0 = E1 / Z;
                    o += p0 * (float)cs[t] + (p1 - p0) * (float)n11[t];
                }
                o *= 0.25f;
            }
        }
        out[((size_t)b * 1024 + s) * 512 + (h << 6) + lane] = o;
    }
}

extern "C" void kernel_launch(void* const* d_in, const int* in_sizes, int n_in,
                              void* d_out, int out_size, void* d_ws, size_t ws_size,
                              hipStream_t stream) {
    const float* x  = (const float*)d_in[0];
    const float* Wq = (const float*)d_in[1];
    const float* Wk = (const float*)d_in[2];
    const float* Wv = (const float*)d_in[3];
    float* out = (float*)d_out;

    u64* bits = (u64*)d_ws;                          // 1.5 MiB
    u64* vt   = bits + (size_t)3 * 4 * 2 * 8 * 1024; // 0.5 MiB
    ushort_t* xh = (ushort_t*)((char*)d_ws + (2u << 20));
    ushort_t* xl = xh + (size_t)2048 * 512;
    ushort_t* wh = xl + (size_t)2048 * 512;
    ushort_t* wl = wh + (size_t)1536 * 512;

    cvt_split<<<dim3(896), 256, 0, stream>>>(x, Wq, Wk, Wv, xh, xl, wh, wl);
    gemm_mfma_lif_pack2<<<dim3(32, 24), 256, 0, stream>>>(xh, xl, wh, wl, bits);
    v_transpose2<<<dim3(2, 8, 4), 256, 0, stream>>>(bits, vt);
    spike_attn4<<<dim3(64, 8, 2), 256, 0, stream>>>(bits, vt, out);
}

// Round 8
// 49.188 us; speedup vs baseline: 1.0782x; 1.0782x over previous
//
#include <hip/hip_runtime.h>
#include <cstdint>

typedef unsigned long long u64;
typedef unsigned short ushort_t;
typedef __attribute__((ext_vector_type(8))) short short8;   // 8 bf16 = 4 VGPR
typedef __attribute__((ext_vector_type(4))) float f32x4;

#define RFL(x) __builtin_amdgcn_readfirstlane(x)

__device__ __forceinline__ unsigned short f2bf(float f) {   // RNE f32->bf16
    union { float f; unsigned u; } v; v.f = f;
    unsigned r = v.u + 0x7FFFu + ((v.u >> 16) & 1u);
    return (unsigned short)(r >> 16);
}
__device__ __forceinline__ float bf2f(unsigned short h) {
    union { float f; unsigned u; } v; v.u = ((unsigned)h) << 16;
    return v.f;
}

__device__ __forceinline__ void gload_lds16(const void* g, void* l) {
    __builtin_amdgcn_global_load_lds(
        (const __attribute__((address_space(1))) unsigned int*)g,
        (__attribute__((address_space(3))) unsigned int*)l, 16, 0, 0);
}

// Dims: B=2, S=1024, C=512, H=8, hd=64, T=4.
// bits: [3][4(t)][2(b)][8(h)][1024(s)] u64  (bit d = channel)
// vt:   [2(b)][8(h)][4(t)][16(w)][64(d)] u64 (bit j = k-index w*64+j)
// ws: bits 1.5M | vt 0.5M | xh 2M | xl 2M | wh 1.5M | wl 1.5M | csbuf 16K

#define AH_OFF 0
#define AL_OFF 8192
#define BH_OFF 16384
#define BL_OFF 24576
#define BUF_STRIDE 32768

// ---------------- Kernel C: one-shot f32 -> split-bf16; block 896 zeroes csbuf.
__global__ __launch_bounds__(256) void cvt_split(
    const float* __restrict__ x,
    const float* __restrict__ Wq, const float* __restrict__ Wk,
    const float* __restrict__ Wv,
    ushort_t* __restrict__ xh, ushort_t* __restrict__ xl,
    ushort_t* __restrict__ wh, ushort_t* __restrict__ wl,
    unsigned* __restrict__ csbuf)
{
    const int bid = blockIdx.x;
    if (bid == 896) {           // zero csbuf [16][4][64] u32
#pragma unroll
        for (int i = 0; i < 16; ++i)
            csbuf[i * 256 + threadIdx.x] = 0u;
        return;
    }
    const float* s;
    ushort_t *hd, *ld;
    if (bid < 512) {
        const size_t j = (size_t)bid * 2048 + (size_t)threadIdx.x * 8;
        s = x + j; hd = xh + j; ld = xl + j;
    } else {
        const size_t j = (size_t)(bid - 512) * 2048 + (size_t)threadIdx.x * 8;
        const int mat = (int)(j >> 18);           // 512*512 elems per matrix
        const size_t off = j & 262143;
        s = ((mat == 0) ? Wq : (mat == 1) ? Wk : Wv) + off;
        hd = wh + j; ld = wl + j;
    }
    const float4 a = *(const float4*)s;
    const float4 b = *(const float4*)(s + 4);
    const float va[8] = {a.x, a.y, a.z, a.w, b.x, b.y, b.z, b.w};
    short8 h8, l8;
#pragma unroll
    for (int i = 0; i < 8; ++i) {
        const unsigned short hi = f2bf(va[i]);
        h8[i] = (short)hi;
        l8[i] = (short)f2bf(va[i] - bf2f(hi));
    }
    *(short8*)hd = h8;
    *(short8*)ld = l8;
}

// ---------------- MFMA GEMM v3: double-buffered prefetch (T3-minimum 2-phase).
// Stage tile it+1 BEFORE computing tile it; one __syncthreads per iter (its
// implicit vmcnt/lgkm drain lands after the compute covers the load latency).
// Buffer safety: reads of buf^1 completed before the PREVIOUS iter-end
// barrier, so this iter's prefetch into buf^1 is race-free.
// y accumulation order identical to R4-R7 -> bitwise-identical spikes.
__global__ __launch_bounds__(256) void gemm_mfma_lif_pack3(
    const ushort_t* __restrict__ xh, const ushort_t* __restrict__ xl,
    const ushort_t* __restrict__ wh, const ushort_t* __restrict__ wl,
    u64* __restrict__ bits)
{
    __shared__ __align__(16) char smem[65536];

    const int tid  = threadIdx.x;
    const int lane = tid & 63;
    const int wv   = RFL(tid >> 6);
    const int bx  = blockIdx.x;     // 32 row tiles of 64
    const int byn = blockIdx.y;     // 24 = 3 mat * 8 heads
    const int mat = byn >> 3, h = byn & 7;

    const int wm = wv >> 1, wn = wv & 1;
    const int lg = lane >> 4, lr = lane & 15;

    // staging: lane l writes LDS slot (l&7) of row stripe*8+(l>>3); pre-apply
    // the read-side XOR on the GLOBAL source (rule #21) so reads see logical k.
    const int lrow8 = lane >> 3;
    const int koff  = ((lane & 7) ^ lrow8) * 8;   // bf16 elems in 64-k chunk

    f32x4 acc[2][2] = {{{0.f,0.f,0.f,0.f},{0.f,0.f,0.f,0.f}},
                       {{0.f,0.f,0.f,0.f},{0.f,0.f,0.f,0.f}}};

#define STAGE(buf, k0)                                                        \
    {                                                                         \
        const int base_ = (buf) * BUF_STRIDE;                                 \
        _Pragma("unroll")                                                     \
        for (int sp = 0; sp < 2; ++sp) {                                      \
            const int stripe = wv * 2 + sp;                                   \
            const int row = stripe * 8 + lrow8;                               \
            const size_t aoff = (size_t)(bx * 64 + row) * 512 + (k0) + koff;  \
            const size_t boff = (size_t)(byn * 64 + row) * 512 + (k0) + koff; \
            gload_lds16(xh + aoff, smem + base_ + AH_OFF + stripe * 1024);    \
            gload_lds16(xl + aoff, smem + base_ + AL_OFF + stripe * 1024);    \
            gload_lds16(wh + boff, smem + base_ + BH_OFF + stripe * 1024);    \
            gload_lds16(wl + boff, smem + base_ + BL_OFF + stripe * 1024);    \
        }                                                                     \
    }

    STAGE(0, 0);
    __syncthreads();

    for (int it = 0; it < 8; ++it) {
        const int cur = it & 1;
        if (it < 7) STAGE(cur ^ 1, (it + 1) * 64);

        const int base = cur * BUF_STRIDE;
#pragma unroll
        for (int kk = 0; kk < 64; kk += 32) {
            const int slotb = (kk >> 3) + lg;
            short8 ah[2], al[2], bh2[2], bl2[2];
#pragma unroll
            for (int fm = 0; fm < 2; ++fm) {
                const int row = wm * 32 + fm * 16 + lr;
                const int off = base + row * 128 + ((slotb ^ (row & 7)) << 4);
                ah[fm] = *(const short8*)(smem + AH_OFF + off);
                al[fm] = *(const short8*)(smem + AL_OFF + off);
            }
#pragma unroll
            for (int fn = 0; fn < 2; ++fn) {
                const int row = wn * 32 + fn * 16 + lr;
                const int off = base + row * 128 + ((slotb ^ (row & 7)) << 4);
                bh2[fn] = *(const short8*)(smem + BH_OFF + off);
                bl2[fn] = *(const short8*)(smem + BL_OFF + off);
            }
#pragma unroll
            for (int fm = 0; fm < 2; ++fm)
#pragma unroll
                for (int fn = 0; fn < 2; ++fn) {
                    acc[fm][fn] = __builtin_amdgcn_mfma_f32_16x16x32_bf16(
                        ah[fm], bh2[fn], acc[fm][fn], 0, 0, 0);
                    acc[fm][fn] = __builtin_amdgcn_mfma_f32_16x16x32_bf16(
                        ah[fm], bl2[fn], acc[fm][fn], 0, 0, 0);
                    acc[fm][fn] = __builtin_amdgcn_mfma_f32_16x16x32_bf16(
                        al[fm], bh2[fn], acc[fm][fn], 0, 0, 0);
                }
        }
        __syncthreads();
    }
#undef STAGE

    // ---- epilogue: y tile -> LDS (f32, pad 65), then LIF + ballot pack.
    float* yl = (float*)smem;
#pragma unroll
    for (int fm = 0; fm < 2; ++fm)
#pragma unroll
        for (int fn = 0; fn < 2; ++fn)
#pragma unroll
            for (int reg = 0; reg < 4; ++reg) {
                const int m_loc = wm * 32 + fm * 16 + lg * 4 + reg;
                const int n_loc = wn * 32 + fn * 16 + lr;
                yl[m_loc * 65 + n_loc] = acc[fm][fn][reg];
            }
    __syncthreads();

    for (int r = 0; r < 16; ++r) {
        const int lrow = wv * 16 + r;
        const float y = yl[lrow * 65 + lane];
        float v = 0.f;
        int sp[4];
#pragma unroll
        for (int t = 0; t < 4; ++t) {
            v = v + (y - v) * 0.5f;
            const int s = (v - 1.0f >= 0.f) ? 1 : 0;
            v = s ? 0.f : v;
            sp[t] = s;
        }
        const int grow = bx * 64 + lrow;
        const int bb = grow >> 10;
        const int ss = grow & 1023;
        u64* dst = bits + (((size_t)(mat * 4) * 2 + bb) * 8 + h) * 1024 + ss;
#pragma unroll
        for (int t = 0; t < 4; ++t) {
            const u64 msk = __ballot(sp[t]);
            if (lane == 0) dst[(size_t)t * (2 * 8 * 1024)] = msk;
        }
    }
}

// ---------------- Kernel T3: v bit-transpose + cs (column-count) accumulation.
// cs was recomputed by all 64 attn blocks per (b,h) — hoisted here (R7 delta
// attribution: attn4 ~19us, mostly the redundant cs loop).
__global__ __launch_bounds__(256) void v_transpose3(
    const u64* __restrict__ bits,
    u64* __restrict__ vt,
    unsigned* __restrict__ csbuf)
{
    const int lane = threadIdx.x & 63;
    const int t  = threadIdx.x >> 6;
    const int b  = blockIdx.x;
    const int h  = blockIdx.y;
    const int wg = blockIdx.z;
    const int bh = b * 8 + h;
    const u64* __restrict__ src = bits + (((size_t)(2 * 4 + t) * 2 + b) * 8 + h) * 1024;
    u64* __restrict__ dst = vt + ((size_t)bh * 4 + t) * 1024;
    unsigned partial = 0;
    for (int wi = 0; wi < 4; ++wi) {
        const int w = wg * 4 + wi;
        const u64 vword = src[(w << 6) + lane];
        u64 myword = 0;
#pragma unroll
        for (int d = 0; d < 64; ++d) {
            const u64 m = __ballot((int)((vword >> d) & 1ull));
            if (lane == d) myword = m;
        }
        dst[(w << 6) + lane] = myword;
        partial += (unsigned)__popcll(myword);
    }
    atomicAdd(&csbuf[bh * 256 + t * 64 + lane], partial);  // device-scope, exact
}

// ---------------- Kernel B5: precomputed cs + two-level screen + exact path.
__global__ __launch_bounds__(256) void spike_attn5(
    const u64* __restrict__ bits,
    const u64* __restrict__ vt,
    const unsigned* __restrict__ csbuf,
    float* __restrict__ out)
{
    const int lane = threadIdx.x & 63;
    const int wave = RFL((int)(threadIdx.x >> 6));
    const int rt = blockIdx.x;   // 64 tiles of 16 rows
    const int h  = blockIdx.y;
    const int b  = blockIdx.z;

    const int bh = b * 8 + h;
    const u64* __restrict__ qb  = bits + (size_t)bh * 1024;
    const u64* __restrict__ kb  = bits + (size_t)(64 + bh) * 1024;
    const u64* __restrict__ vtb = vt + (size_t)bh * 4096;

    int cs[4];
#pragma unroll
    for (int t = 0; t < 4; ++t)
        cs[t] = (int)csbuf[bh * 256 + t * 64 + lane];
    const float base = (float)(cs[0] + cs[1] + cs[2] + cs[3]) * (1.0f / 4096.0f);

    const float E1 = 0.36787944117144233f;  // expf(-1)
    const int s0 = rt * 16 + wave * 4;      // 4 rows per wave

#pragma unroll
    for (int r = 0; r < 4; ++r) {
        const int s = s0 + r;
        const u64 q0 = qb[s];
        const u64 q1 = qb[16384 + s];
        const u64 q2 = qb[32768 + s];
        const u64 q3 = qb[49152 + s];
        const int c0 = (int)__popcll(q0), c1 = (int)__popcll(q1);
        const int c2 = (int)__popcll(q2), c3 = (int)__popcll(q3);

        // level-1: LIF recurrence on c_t (exact upper bound incl. floors)
        unsigned B = (unsigned)(c0 << 2);
        unsigned mB = B;
        B = (B >> 1) + (unsigned)(c1 << 2); mB = max(mB, B);
        B = (B >> 1) + (unsigned)(c2 << 2); mB = max(mB, B);
        B = (B >> 1) + (unsigned)(c3 << 2); mB = max(mB, B);

        float o = base;
        if (mB >= 64u) {            // wave-uniform; minority of rows
            // level-2: spike requires max_t pc_t >= 9 somewhere
            u64 any = 0;
            for (int w = 0; w < 16; ++w) {
                const int ko = (w << 6) + lane;
                const int pc0 = (int)__popcll(kb[ko]          & q0);
                const int pc1 = (int)__popcll(kb[16384 + ko] & q1);
                const int pc2 = (int)__popcll(kb[32768 + ko] & q2);
                const int pc3 = (int)__popcll(kb[49152 + ko] & q3);
                const int mx = max(max(pc0, pc1), max(pc2, pc3));
                any |= __ballot(mx >= 9);
            }
            if (any) {              // wave-uniform; essentially never
                int msum[4] = {0, 0, 0, 0}, n11[4] = {0, 0, 0, 0};
                for (int w = 0; w < 16; ++w) {
                    const int ko = (w << 6) + lane;
                    const int pcs[4] = {
                        (int)__popcll(kb[ko]          & q0),
                        (int)__popcll(kb[16384 + ko] & q1),
                        (int)__popcll(kb[32768 + ko] & q2),
                        (int)__popcll(kb[49152 + ko] & q3)};
                    unsigned u = 0;
#pragma unroll
                    for (int t = 0; t < 4; ++t) {
                        u = (u >> 1) + (unsigned)(pcs[t] << 2);  // 64ths; exact
                        const int spk = (u >= 64u) ? 1 : 0;
                        const u64 msk = __ballot(spk);
                        u = spk ? 0u : u;
                        msum[t] += (int)__popcll(msk);
                        n11[t]  += (int)__popcll(msk & vtb[t * 1024 + ko]);
                    }
                }
                o = 0.f;
#pragma unroll
                for (int t = 0; t < 4; ++t) {
                    const float mf = (float)msum[t];
                    const float Z  = mf + (1024.f - mf) * E1;
                    const float p1 = 1.0f / Z;
                    const float p0 = E1 / Z;
                    o += p0 * (float)cs[t] + (p1 - p0) * (float)n11[t];
                }
                o *= 0.25f;
            }
        }
        out[((size_t)b * 1024 + s) * 512 + (h << 6) + lane] = o;
    }
}

extern "C" void kernel_launch(void* const* d_in, const int* in_sizes, int n_in,
                              void* d_out, int out_size, void* d_ws, size_t ws_size,
                              hipStream_t stream) {
    const float* x  = (const float*)d_in[0];
    const float* Wq = (const float*)d_in[1];
    const float* Wk = (const float*)d_in[2];
    const float* Wv = (const float*)d_in[3];
    float* out = (float*)d_out;

    u64* bits = (u64*)d_ws;                          // 1.5 MiB
    u64* vt   = bits + (size_t)3 * 4 * 2 * 8 * 1024; // 0.5 MiB
    ushort_t* xh = (ushort_t*)((char*)d_ws + (2u << 20));
    ushort_t* xl = xh + (size_t)2048 * 512;
    ushort_t* wh = xl + (size_t)2048 * 512;
    ushort_t* wl = wh + (size_t)1536 * 512;
    unsigned* csbuf = (unsigned*)(wl + (size_t)1536 * 512);  // 16 KiB @ 9 MiB

    cvt_split<<<dim3(897), 256, 0, stream>>>(x, Wq, Wk, Wv, xh, xl, wh, wl, csbuf);
    gemm_mfma_lif_pack3<<<dim3(32, 24), 256, 0, stream>>>(xh, xl, wh, wl, bits);
    v_transpose3<<<dim3(2, 8, 4), 256, 0, stream>>>(bits, vt, csbuf);
    spike_attn5<<<dim3(64, 8, 2), 256, 0, stream>>>(bits, vt, csbuf, out);
}